// Round 6
// baseline (165.713 us; speedup 1.0000x reference)
//
#include <hip/hip_runtime.h>
#include <hip/hip_bf16.h>

#define C_IN  64
#define C_OUT 128
#define KK    27
#define HH    100000
#define TGB   196          // transpose blocks; each handles 8 strips of 64 rows (1568 >= 1563)
#define TSTRIPS 1563       // ceil(HH/64)
#define WB    108          // weight-convert blocks (108*2048 = 221184 elems)
#define NBLK  391          // ceil(HH/256)

typedef __attribute__((ext_vector_type(8))) short s8v;    // 8 bf16 (MFMA A/B frag)
typedef __attribute__((ext_vector_type(4))) float f32x4;  // MFMA C/D frag
typedef __attribute__((ext_vector_type(4))) float f4v;    // NT-capable float4
typedef __attribute__((ext_vector_type(4))) int   i4v;    // NT-capable int4

__device__ inline unsigned short f2bf(float f) {
    __hip_bfloat16 h = __float2bfloat16(f);
    return *reinterpret_cast<unsigned short*>(&h);
}

__device__ inline void dma16(const void* g, void* l) {
    __builtin_amdgcn_global_load_lds((const __attribute__((address_space(1))) void*)g,
                                     (__attribute__((address_space(3))) void*)l, 16, 0, 0);
}

// ---- prep: transpose x -> xt (bf16, [h][64] plain, + zeroed shadow row at h=HH),
//      W -> wk (bf16, [k][o][64] XOR-swizzled: phys chunk pj holds logical pj^(o&7)) ----
// Grid-stride fat blocks (196 x 8 strips) to amortize block dispatch; float4 NT loads.
__global__ __launch_bounds__(256) void prep_kernel(const float* __restrict__ x,
                                                   const float* __restrict__ w,
                                                   unsigned short* __restrict__ xt,
                                                   unsigned short* __restrict__ wk) {
    const int tid = threadIdx.x;
    if (blockIdx.x < TGB) {
        __shared__ __align__(16) unsigned short ts[64 * 72];
        for (int s = 0; s < 8; ++s) {
            int strip = blockIdx.x * 8 + s;
            if (strip >= TSTRIPS) break;                  // uniform within block
            const int hbase = strip * 64;
            #pragma unroll
            for (int it = 0; it < 4; ++it) {
                int t = it * 256 + tid;                   // 64c x 16 h-quads
                int c = t >> 4, hg4 = t & 15;
                int hg = hbase + hg4 * 4;
                f4v v = (f4v){0.f, 0.f, 0.f, 0.f};
                if (hg < HH)
                    v = __builtin_nontemporal_load((const f4v*)&x[(size_t)c * HH + hg]);
                ts[(hg4 * 4 + 0) * 72 + c] = f2bf(v.x);
                ts[(hg4 * 4 + 1) * 72 + c] = f2bf(v.y);
                ts[(hg4 * 4 + 2) * 72 + c] = f2bf(v.z);
                ts[(hg4 * 4 + 3) * 72 + c] = f2bf(v.w);
            }
            __syncthreads();
            #pragma unroll
            for (int it = 0; it < 2; ++it) {
                int u = it * 256 + tid;                   // 64 rows x 8 chunks of 16B
                int hl = u >> 3, part = u & 7;
                int hg = hbase + hl;
                if (hg < HH)
                    __builtin_nontemporal_store(*(const i4v*)&ts[hl * 72 + part * 8],
                                                (i4v*)&xt[(size_t)hg * 64 + part * 8]);
            }
            __syncthreads();                              // ts reused next strip
        }
    } else {
        int b = blockIdx.x - TGB;
        // zeroed shadow rows HH.. (gather target for OOB/negative neigh indices)
        if (b == 0 && tid < 64) {
            i4v z = (i4v){0, 0, 0, 0};
            *(i4v*)&xt[(size_t)HH * 64 + tid * 8] = z;
        }
        int base = b * 2048 + tid;
        #pragma unroll
        for (int j = 0; j < 8; ++j) {
            int t = base + j * 256;           // wk index: t = k*8192 + o*64 + jj
            int jj = t & 63, o = (t >> 6) & 127, kx = t >> 13;
            int lc = (jj >> 3) ^ (o & 7);     // logical chunk
            int c  = lc * 8 + (jj & 7);
            wk[t] = f2bf(w[(size_t)o * (C_IN * KK) + c * KK + kx]);
        }
    }
}

// ---------------- main gather-GEMM ----------------
// block 256 thr = 4 waves; tile M=128 (all o) x N=256 h; wave w: h strip [w*64, w*64+64)
// W: TRIPLE-buffered LDS via async DMA, k+2 lookahead. B: direct global->VGPR, k+1 ahead.
// Per-iter vmcnt ledger (program order pinned by sched_barrier after DMA issue):
//   iter k issues: DMA(k+2)[4] then g(k+1)[8].
//   pre-MFMA-k compiler wait for g(k) (issued iter k-1, AFTER DMA(k+1)) -> FIFO retires
//   DMA(k+1) too => the barrier at end of iter k needs NO vmcnt wait at all, only
//   lgkmcnt(0) (drain ds_reads of w_s[k%3] before anyone DMAs into it at iter k+1).
//   Both DMA and gathers now get >= 1 full iteration of flight time; no lockstep
//   post-MFMA DMA stall.
// LDS: 3 x 16 KB w_s + 27 KB neigh = 76.8 KB -> 2 blocks/CU (<= 80 KB).
__global__ __launch_bounds__(256, 2) void conv_main(const unsigned short* __restrict__ xt,
                                                    const unsigned short* __restrict__ wk,
                                                    const int* __restrict__ neigh,
                                                    float* __restrict__ out) {
    __shared__ int neigh_s[256 * KK];                            // 27648 B, [h][k]
    __shared__ __align__(16) unsigned short w_s[3 * 128 * 64];   // 3 x 16 KB, XOR-swizzled rows

    const int tid  = threadIdx.x;
    const int wave = tid >> 6;
    const int lane = tid & 63;
    const int col  = lane & 15;
    const int quad = lane >> 4;
    const int hbase = blockIdx.x * 256;

    // ---- issue W DMA for k=0 into buf 0 ----
    #pragma unroll
    for (int i = 0; i < 4; ++i) {
        int row_base = wave * 8 + i * 32; // 8 rows = 1024 B per inst
        dma16(wk + row_base * 64 + lane * 8, &w_s[0 * 8192 + row_base * 64]);
    }

    // ---- early B0 gather: indices straight from global neigh (one-time; latency
    //      overlapped with the whole neigh_s staging phase below) ----
    int4 b0[2][4], b1[2][4];
    {
        #pragma unroll
        for (int nt = 0; nt < 4; ++nt) {
            int n  = wave * 64 + nt * 16 + col;
            int hg = hbase + n;
            int idx = (hg < HH) ? neigh[(size_t)hg * KK] : -1;
            int idxc = (idx < 0) ? HH : idx;                 // row HH = zeros
            const unsigned short* base = xt + (size_t)idxc * 64 + quad * 8;
            b0[0][nt] = *(const int4*)(base);
            b0[1][nt] = *(const int4*)(base + 32);
        }
    }

    // ---- stage neighbor indices (coalesced) ----
    #pragma unroll
    for (int j = 0; j < KK; ++j) {
        int i = j * 256 + tid;                // 6912 = 27*256 exactly
        int hl = i / KK, kx = i - hl * KK;
        int hg = hbase + hl;
        neigh_s[i] = (hg < HH) ? neigh[(size_t)hg * KK + kx] : -1;
    }

    // ---- issue W DMA for k=1 into buf 1 ----
    #pragma unroll
    for (int i = 0; i < 4; ++i) {
        int row_base = wave * 8 + i * 32;
        dma16(wk + (size_t)1 * (C_OUT * C_IN) + row_base * 64 + lane * 8,
              &w_s[1 * 8192 + row_base * 64]);
    }

    f32x4 acc[8][4];
    #pragma unroll
    for (int mt = 0; mt < 8; ++mt)
        #pragma unroll
        for (int nt = 0; nt < 4; ++nt)
            acc[mt][nt] = (f32x4){0.f, 0.f, 0.f, 0.f};

    __syncthreads();   // drains everything: w0,w1 staged, b0 landed, neigh_s ready

    // ---- B-fragment loader: 8 x 16B UNCONDITIONAL gathers into VGPRs ----
    auto loadB = [&](int kk, int4 (&frag)[2][4]) {
        #pragma unroll
        for (int nt = 0; nt < 4; ++nt) {
            int n = wave * 64 + nt * 16 + col;
            int idx = neigh_s[n * KK + kk];
            int idxc = (idx < 0) ? HH : idx;                 // row HH = zeros
            const unsigned short* base = xt + (size_t)idxc * 64 + quad * 8;
            frag[0][nt] = *(const int4*)(base);
            frag[1][nt] = *(const int4*)(base + 32);
        }
    };

    int wc = 0;  // w_s buffer index holding slice k (uniform; == k % 3)

    // ---- one pipeline step: consume `cur`@k on w_s[wc]; issue DMA(k+2), g(k+1) ----
    auto step = [&](int k, int4 (&cur)[2][4], int4 (&nxt)[2][4], bool dma_far, bool do_next) {
        if (dma_far) {
            int wc2 = wc + 2; if (wc2 >= 3) wc2 -= 3;
            const unsigned short* src = wk + (size_t)(k + 2) * (C_OUT * C_IN);
            unsigned short* dst = &w_s[wc2 * 8192];
            #pragma unroll
            for (int i = 0; i < 4; ++i) {
                int row_base = wave * 8 + i * 32;
                dma16(src + row_base * 64 + lane * 8, dst + row_base * 64);
            }
            // pin program order: DMAs older than the gathers below, so the pre-MFMA
            // wait for g(k+1) at iter k+1 provably retires DMA(k+1) (FIFO vmcnt).
            __builtin_amdgcn_sched_barrier(0);
        }
        if (do_next)
            loadB(k + 1, nxt);   // stays in flight across the barrier below

        // MFMA phase on w_s[wc] + cur (compiler inserts counted vmcnt wait for cur)
        const unsigned short* wp = &w_s[wc * 8192];
        #pragma unroll
        for (int ch = 0; ch < 2; ++ch) {
            const int pc = (ch * 4 + quad) ^ (col & 7);   // physical chunk (XOR swizzle)
            #pragma unroll
            for (int mt = 0; mt < 8; ++mt) {
                s8v a = *(const s8v*)&wp[(mt * 16 + col) * 64 + pc * 8];
                #pragma unroll
                for (int nt = 0; nt < 4; ++nt) {
                    s8v b = __builtin_bit_cast(s8v, cur[ch][nt]);
                    acc[mt][nt] = __builtin_amdgcn_mfma_f32_16x16x32_bf16(a, b, acc[mt][nt], 0, 0, 0);
                }
            }
        }

        if (do_next) {
            // only drain LDS reads of w_s[wc] (it gets DMA'd at iter k+1); no vmcnt wait.
            asm volatile("s_waitcnt lgkmcnt(0)" ::: "memory");
            __builtin_amdgcn_s_barrier();
        }
        ++wc; if (wc == 3) wc = 0;
    };

    #pragma unroll 1
    for (int k = 0; k < 24; k += 2) {        // k = 0..23: full pipeline (k+2 <= 25)
        step(k,     b0, b1, true, true);
        step(k + 1, b1, b0, true, true);
    }
    step(24, b0, b1, true,  true);           // issues DMA(26), g(25)
    step(25, b1, b0, false, true);           // issues g(26)
    step(26, b0, b1, false, false);          // final: no prefetch, no barrier

    // ---- epilogue: D row = quad*4+r (o), col = lane&15 (h); relu + fp32 store ----
    #pragma unroll
    for (int mt = 0; mt < 8; ++mt) {
        #pragma unroll
        for (int nt = 0; nt < 4; ++nt) {
            int hg = hbase + wave * 64 + nt * 16 + col;
            if (hg < HH) {
                #pragma unroll
                for (int r = 0; r < 4; ++r) {
                    int o = mt * 16 + quad * 4 + r;
                    float v = acc[mt][nt][r];
                    out[(size_t)o * HH + hg] = v > 0.f ? v : 0.f;
                }
            }
        }
    }
}

extern "C" void kernel_launch(void* const* d_in, const int* in_sizes, int n_in,
                              void* d_out, int out_size, void* d_ws, size_t ws_size,
                              hipStream_t stream) {
    const float* data_in = (const float*)d_in[0];
    const int*   neigh   = (const int*)d_in[1];
    const float* weight  = (const float*)d_in[2];
    float* out = (float*)d_out;

    unsigned short* xt = (unsigned short*)d_ws;            // (H+8)*64 bf16 ~= 12.8 MB
    unsigned short* wk = xt + (size_t)(HH + 8) * 64;       // 27*128*64 bf16 = 442 KB

    prep_kernel<<<TGB + WB, 256, 0, stream>>>(data_in, weight, xt, wk);
    conv_main<<<NBLK, 256, 0, stream>>>(xt, wk, neigh, out);
}

// Round 7
// 154.960 us; speedup vs baseline: 1.0694x; 1.0694x over previous
//
#include <hip/hip_runtime.h>
#include <hip/hip_bf16.h>

#define C_IN  64
#define C_OUT 128
#define KK    27
#define HH    100000
#define TB    1563         // transpose blocks = ceil(HH/64)
#define WB    108          // weight-convert blocks (108*2048 = 221184 elems)
#define NBLK  391          // ceil(HH/256)
#define NSLICE (2 * KK)    // 54 (half, k) slices
#define XTROW 32           // elems per half-row (64 B)
#define XTSZ  ((HH + 8) * XTROW)

typedef __attribute__((ext_vector_type(8))) short s8v;    // 8 bf16 (MFMA A/B frag)
typedef __attribute__((ext_vector_type(4))) float f32x4;  // MFMA C/D frag
typedef __attribute__((ext_vector_type(4))) float f4v;
typedef __attribute__((ext_vector_type(4))) int   i4v;

__device__ inline unsigned short f2bf(float f) {
    __hip_bfloat16 h = __float2bfloat16(f);
    return *reinterpret_cast<unsigned short*>(&h);
}

__device__ inline void dma16(const void* g, void* l) {
    __builtin_amdgcn_global_load_lds((const __attribute__((address_space(1))) void*)g,
                                     (__attribute__((address_space(3))) void*)l, 16, 0, 0);
}

// ---- prep ----
// x -> xt0[h][32] (c 0..31), xt1[h][32] (c 32..63), bf16, 64B rows, + zero shadow row at h=HH.
// W -> wk[half][k][o][32], bf16, XOR-swizzled: phys 16B chunk pj holds logical pj^(o&3).
__global__ __launch_bounds__(256) void prep_kernel(const float* __restrict__ x,
                                                   const float* __restrict__ w,
                                                   unsigned short* __restrict__ xt,
                                                   unsigned short* __restrict__ wk) {
    const int tid = threadIdx.x;
    unsigned short* xt0 = xt;
    unsigned short* xt1 = xt + XTSZ;
    if (blockIdx.x < TB) {
        __shared__ __align__(16) unsigned short ts[64 * 72];
        const int hbase = blockIdx.x * 64;
        // 64c x 64h via float4 loads over h (HH % 4 == 0: a float4 is fully in or out)
        #pragma unroll
        for (int it = 0; it < 4; ++it) {
            int t = it * 256 + tid;           // 0..1023
            int c = t >> 4, hg4 = t & 15;
            int hg = hbase + hg4 * 4;
            f4v v = (f4v){0.f, 0.f, 0.f, 0.f};
            if (hg < HH)
                v = __builtin_nontemporal_load((const f4v*)&x[(size_t)c * HH + hg]);
            ts[(hg4 * 4 + 0) * 72 + c] = f2bf(v.x);
            ts[(hg4 * 4 + 1) * 72 + c] = f2bf(v.y);
            ts[(hg4 * 4 + 2) * 72 + c] = f2bf(v.z);
            ts[(hg4 * 4 + 3) * 72 + c] = f2bf(v.w);
        }
        __syncthreads();
        #pragma unroll
        for (int it = 0; it < 2; ++it) {
            int u = it * 256 + tid;           // 64 rows x 8 chunks of 16B
            int hl = u >> 3, part = u & 7;
            int hg = hbase + hl;
            if (hg < HH) {
                unsigned short* dst = (part < 4)
                    ? &xt0[(size_t)hg * XTROW + part * 8]
                    : &xt1[(size_t)hg * XTROW + (part - 4) * 8];
                *(i4v*)dst = *(const i4v*)&ts[hl * 72 + part * 8];
            }
        }
    } else {
        int b = blockIdx.x - TB;
        // zero shadow rows (gather target for OOB/negative neigh indices)
        if (b == 0 && tid < 8) {
            unsigned short* base = (tid < 4) ? xt0 : xt1;
            i4v z = (i4v){0, 0, 0, 0};
            *(i4v*)&base[(size_t)HH * XTROW + (tid & 3) * 8] = z;
        }
        int base = b * 2048 + tid;
        #pragma unroll
        for (int j = 0; j < 8; ++j) {
            int t = base + j * 256;               // 0..221183
            int half = t >= 110592;
            int rem  = t - half * 110592;
            int k  = rem >> 12;                   // 0..26
            int o  = (rem >> 5) & 127;
            int jj = rem & 31;
            int lc = (jj >> 3) ^ (o & 3);         // logical chunk within half
            int c  = half * 32 + lc * 8 + (jj & 7);
            wk[t] = f2bf(w[(size_t)o * (C_IN * KK) + c * KK + k]);
        }
    }
}

// ---------------- main gather-GEMM ----------------
// 4 waves; tile M=128 x N=256 h; wave w: h strip [w*64, w*64+64).
// K-loop runs over 54 (half,k) slices; each slice is a K=32 MFMA step gathering 64B
// xt-half rows. Per-pass gather working set = 6.4 MB (vs 12.8) -> higher L2 hit ->
// fewer L2-miss requests (the measured wall). acc carries across both halves.
// W: triple-buffered 8KB LDS slices, DMA 2 slices ahead; B: gathers 1 slice ahead,
// in flight across the barrier (R6 FIFO-vmcnt scheme: DMA issued before gathers,
// pinned by sched_barrier; pre-MFMA compiler wait for gathers retires older DMAs;
// end-of-iter needs only lgkmcnt(0) + s_barrier).
__global__ __launch_bounds__(256, 2) void conv_main(const unsigned short* __restrict__ xt,
                                                    const unsigned short* __restrict__ wk,
                                                    const int* __restrict__ neigh,
                                                    float* __restrict__ out) {
    __shared__ int neigh_s[256 * KK];                            // 27648 B, [h][k]
    __shared__ __align__(16) unsigned short w_s[3 * 128 * XTROW]; // 3 x 8 KB

    const int tid  = threadIdx.x;
    const int wave = tid >> 6;
    const int lane = tid & 63;
    const int col  = lane & 15;
    const int quad = lane >> 4;
    const int hbase = blockIdx.x * 256;
    const unsigned short* xh[2] = { xt, xt + XTSZ };

    // ---- issue W DMA for slice 0 into buf 0 ----
    #pragma unroll
    for (int i = 0; i < 2; ++i) {
        int row_base = wave * 16 + i * 64;    // 16 rows x 64B = 1024 B per inst
        dma16(wk + row_base * XTROW + lane * 8, &w_s[0 * 4096 + row_base * XTROW]);
    }

    // ---- early B0 gather: indices straight from global neigh (overlapped with staging) ----
    int4 b0[4], b1[4];
    #pragma unroll
    for (int nt = 0; nt < 4; ++nt) {
        int n  = wave * 64 + nt * 16 + col;
        int hg = hbase + n;
        int idx = (hg < HH) ? neigh[(size_t)hg * KK] : -1;
        int idxc = (idx < 0) ? HH : idx;
        b0[nt] = *(const int4*)(xh[0] + (size_t)idxc * XTROW + quad * 8);
    }

    // ---- stage neighbor indices (coalesced) ----
    #pragma unroll
    for (int j = 0; j < KK; ++j) {
        int i = j * 256 + tid;                // 6912 = 27*256 exactly
        int hl = i / KK, kx = i - hl * KK;
        int hg = hbase + hl;
        neigh_s[i] = (hg < HH) ? neigh[(size_t)hg * KK + kx] : -1;
    }

    // ---- issue W DMA for slice 1 into buf 1 ----
    #pragma unroll
    for (int i = 0; i < 2; ++i) {
        int row_base = wave * 16 + i * 64;
        dma16(wk + (size_t)1 * (128 * XTROW) + row_base * XTROW + lane * 8,
              &w_s[1 * 4096 + row_base * XTROW]);
    }

    f32x4 acc[8][4];
    #pragma unroll
    for (int mt = 0; mt < 8; ++mt)
        #pragma unroll
        for (int nt = 0; nt < 4; ++nt)
            acc[mt][nt] = (f32x4){0.f, 0.f, 0.f, 0.f};

    __syncthreads();   // w0,w1 staged issued; b0 landed; neigh_s ready; vmcnt drains to 0

    // ---- B loader for slice s: half = s>=27, k = s-27*half; 4 x 16B gathers ----
    auto loadB = [&](int s, int4 (&frag)[4]) {
        int half = s >= KK;
        int kk = s - (half ? KK : 0);
        const unsigned short* xb = xh[half];
        #pragma unroll
        for (int nt = 0; nt < 4; ++nt) {
            int n = wave * 64 + nt * 16 + col;
            int idx = neigh_s[n * KK + kk];
            int idxc = (idx < 0) ? HH : idx;
            frag[nt] = *(const int4*)(xb + (size_t)idxc * XTROW + quad * 8);
        }
    };

    int wc = 0;  // buffer holding slice s (== s % 3)

    auto step = [&](int s, int4 (&cur)[4], int4 (&nxt)[4], bool dma_far, bool do_next) {
        if (dma_far) {
            int wc2 = wc + 2; if (wc2 >= 3) wc2 -= 3;
            const unsigned short* src = wk + (size_t)(s + 2) * (128 * XTROW);
            unsigned short* dst = &w_s[wc2 * 4096];
            #pragma unroll
            for (int i = 0; i < 2; ++i) {
                int row_base = wave * 16 + i * 64;
                dma16(src + row_base * XTROW + lane * 8, dst + row_base * XTROW);
            }
            // pin order: DMAs older than the gathers -> pre-MFMA gather wait at s+1
            // retires DMA(s+1) by FIFO, so no vmcnt wait needed at the barrier.
            __builtin_amdgcn_sched_barrier(0);
        }
        if (do_next)
            loadB(s + 1, nxt);   // stays in flight across the barrier below

        // MFMA on w_s[wc] + cur: 8 mt x 4 nt, one K=32 chunk
        const unsigned short* wp = &w_s[wc * 4096];
        #pragma unroll
        for (int mt = 0; mt < 8; ++mt) {
            const int pc = quad ^ (col & 3);          // physical chunk (XOR swizzle)
            s8v a = *(const s8v*)&wp[(mt * 16 + col) * XTROW + pc * 8];
            #pragma unroll
            for (int nt = 0; nt < 4; ++nt) {
                s8v b = __builtin_bit_cast(s8v, cur[nt]);
                acc[mt][nt] = __builtin_amdgcn_mfma_f32_16x16x32_bf16(a, b, acc[mt][nt], 0, 0, 0);
            }
        }

        if (do_next) {
            // drain ds_reads of w_s[wc] (DMA'd again next iter); no vmcnt wait.
            asm volatile("s_waitcnt lgkmcnt(0)" ::: "memory");
            __builtin_amdgcn_s_barrier();
        }
        ++wc; if (wc == 3) wc = 0;
    };

    #pragma unroll 1
    for (int s = 0; s < NSLICE - 2; s += 2) {   // s = 0..51: full pipeline (s+2 <= 53)
        step(s,     b0, b1, true, true);
        step(s + 1, b1, b0, true, true);
    }
    step(NSLICE - 2, b0, b1, false, true);      // s=52: gather s=53, no DMA
    step(NSLICE - 1, b1, b0, false, false);     // s=53: final

    // ---- epilogue: D row = quad*4+r (o), col = lane&15 (h); relu + fp32 store ----
    #pragma unroll
    for (int mt = 0; mt < 8; ++mt) {
        #pragma unroll
        for (int nt = 0; nt < 4; ++nt) {
            int hg = hbase + wave * 64 + nt * 16 + col;
            if (hg < HH) {
                #pragma unroll
                for (int r = 0; r < 4; ++r) {
                    int o = mt * 16 + quad * 4 + r;
                    float v = acc[mt][nt][r];
                    out[(size_t)o * HH + hg] = v > 0.f ? v : 0.f;
                }
            }
        }
    }
}

extern "C" void kernel_launch(void* const* d_in, const int* in_sizes, int n_in,
                              void* d_out, int out_size, void* d_ws, size_t ws_size,
                              hipStream_t stream) {
    const float* data_in = (const float*)d_in[0];
    const int*   neigh   = (const int*)d_in[1];
    const float* weight  = (const float*)d_in[2];
    float* out = (float*)d_out;

    unsigned short* xt = (unsigned short*)d_ws;            // 2 x (H+8)*32 bf16 ~= 12.8 MB
    unsigned short* wk = xt + (size_t)2 * XTSZ;            // 54*128*32 bf16 = 442 KB

    prep_kernel<<<TB + WB, 256, 0, stream>>>(data_in, weight, xt, wk);
    conv_main<<<NBLK, 256, 0, stream>>>(xt, wk, neigh, out);
}